// Round 5
// baseline (89.610 us; speedup 1.0000x reference)
//
#include <hip/hip_runtime.h>
#include <hip/hip_bf16.h>

// Framing op: x [16, 1048576] f32 -> out [16, 2048, 2048] f32
// out[b, f, t] = (f*512 + t >= 1536) ? x[b, f*512 + t - 1536] : 0.0f
//
// GATHER with XCD-contiguous swizzle.
//  - Writes: one f4 per thread, linear gid order -> perfectly sequential
//    streaming stores (same pattern as the 6.9 TB/s fill kernels).
//  - Reads: each input line is read 4x by frames f..f+3, i.e. within ~8
//    consecutive blocks in gid order. Default dispatch round-robins blocks
//    across the 8 XCDs, so re-reads miss the private L2 (round-0: 537 MB
//    HBM traffic). Swizzle bid -> (bid%8)*8192 + bid/8 gives each XCD a
//    contiguous 32 MB output chunk: read reuse distance ~100s of KB, hits
//    the 4 MB per-XCD L2. 65536 blocks % 8 == 0 -> bijective.
// Traffic target: 64 MiB read + 256 MiB write = 335.5 MB -> ~50 us.

typedef float f4 __attribute__((ext_vector_type(4)));

#define T4_PER_B   262144u   // f4 per batch row of x (1048576/4)
#define PREFIX4    384u      // 1536 floats / 4

__global__ __launch_bounds__(256) void gather_frames(
    const f4* __restrict__ x4, f4* __restrict__ out4)
{
    // XCD-contiguous remap: grid = 65536 blocks, 8192 per XCD.
    unsigned bid   = blockIdx.x;
    unsigned sbid  = (bid & 7u) * 8192u + (bid >> 3);
    unsigned gid   = sbid * 256u + threadIdx.x;   // f4 index into out (2^24 total)

    unsigned t4 = gid & 511u;            // f4 within frame (512 per frame)
    unsigned f  = (gid >> 9) & 2047u;    // frame
    unsigned b  = gid >> 20;             // batch

    unsigned i4 = f * 128u + t4;         // f4 pos within padded signal
    f4 v = (f4){0.f, 0.f, 0.f, 0.f};
    if (i4 >= PREFIX4) {
        v = x4[b * T4_PER_B + (i4 - PREFIX4)];
    }
    out4[gid] = v;
}

extern "C" void kernel_launch(void* const* d_in, const int* in_sizes, int n_in,
                              void* d_out, int out_size, void* d_ws, size_t ws_size,
                              hipStream_t stream) {
    const f4* x4 = (const f4*)d_in[0];
    f4* out4 = (f4*)d_out;
    const unsigned n4 = 16u * 2048u * 2048u / 4u;  // 16,777,216 f4
    dim3 block(256);
    dim3 grid(n4 / 256u);                          // 65536 blocks
    gather_frames<<<grid, block, 0, stream>>>(x4, out4);
}

// Round 6
// 85.472 us; speedup vs baseline: 1.0484x; 1.0484x over previous
//
#include <hip/hip_runtime.h>
#include <hip/hip_bf16.h>

// Framing op: x [16, 1048576] f32 -> out [16, 2048, 2048] f32
// out[b, f, t] = (f*512 + t >= 1536) ? x[b, f*512 + t - 1536] : 0.0f
//
// FAT-BLOCK GATHER. One block = 8 consecutive frames of one batch
// = 4096 contiguous f4 of output (16 f4 per thread).
//  - Writes: block-major contiguous -> globally sequential store stream,
//    the exact pattern that hits the 6.9 TB/s fill ceiling (round-0 data).
//  - Reads: the 4x frame-overlap re-reads of an input line all occur
//    WITHIN this block (input window 22 KB fits L1; same CU -> same XCD L2
//    as fallback). Re-read temporal distance ~1.5 strips (~6 KB) -> L1 hit.
//    Inter-block overlap is only the 3-frame (384 f4) leading window
//    (~+24 MB fabric traffic).
//  - No nontemporal hints: loads need caching; stores match fill pattern.
// Traffic: 256 MiB write + ~88 MiB read ~= 344 MB -> ~52 us at 6.7 TB/s.

typedef float f4 __attribute__((ext_vector_type(4)));

#define T4_PER_B   262144u   // f4 per batch row of x (1048576/4)
#define PREFIX4    384u      // 1536 floats / 4
#define F4_FRAME   512u      // f4 per frame (2048/4)
#define HOP4       128u      // f4 per hop (512/4)

__global__ __launch_bounds__(256) void gather8_frames(
    const f4* __restrict__ x4, f4* __restrict__ out4)
{
    const unsigned fg  = blockIdx.x;     // frame group 0..255 (8 frames each)
    const unsigned b   = blockIdx.y;     // batch 0..15
    const unsigned tid = threadIdx.x;

    const unsigned in_base  = b * T4_PER_B;
    const unsigned out_base = b * (2048u * F4_FRAME) + fg * 4096u;
    // input f4 offset of this block's local frame 0, minus zero-prefix
    const int F128 = (int)(fg * 8u * HOP4) - (int)PREFIX4;

#pragma unroll
    for (int s = 0; s < 16; ++s) {
        unsigned o  = tid + 256u * (unsigned)s;  // local output f4 idx 0..4095
        unsigned fl = o >> 9;                    // local frame 0..7
        unsigned t4 = o & 511u;                  // f4 within frame
        int i4 = F128 + (int)(fl * HOP4 + t4);
        f4 v = (f4){0.f, 0.f, 0.f, 0.f};
        if (i4 >= 0) {
            v = x4[in_base + (unsigned)i4];
        }
        out4[out_base + o] = v;
    }
}

extern "C" void kernel_launch(void* const* d_in, const int* in_sizes, int n_in,
                              void* d_out, int out_size, void* d_ws, size_t ws_size,
                              hipStream_t stream) {
    const f4* x4 = (const f4*)d_in[0];
    f4* out4 = (f4*)d_out;
    dim3 block(256);
    dim3 grid(256, 16);   // 2048 frames / 8 per block, 16 batches
    gather8_frames<<<grid, block, 0, stream>>>(x4, out4);
}

// Round 7
// 65.595 us; speedup vs baseline: 1.3661x; 1.3030x over previous
//
#include <hip/hip_runtime.h>
#include <hip/hip_bf16.h>

// Framing op: x [16, 1048576] f32 -> out [16, 2048, 2048] f32
// out[b, f, t] = (f*512 + t >= 1536) ? x[b, f*512 + t - 1536] : 0.0f
//
// LDS-STAGED FAT-BLOCK. One block = 8 consecutive frames of one batch
// = 4096 contiguous f4 (64 KB) of output.
//  Phase 1: stage the block's input window (1408 f4 = 22 KB, incl. 3-frame
//    halo) into LDS. Each input line read from global EXACTLY once per
//    block (halo gives 1.375x amplification total = ~88 MB reads).
//    Wave loads are 1 KB contiguous; ds_writes consecutive -> conflict-free.
//  Phase 2: emit 64 KB as a linear store stream (1 KB per wave-instr,
//    block-major sequential = the 6.9 TB/s fill pattern). LDS reads
//    consecutive -> conflict-free (b128 2-way aliasing is free).
// Why not caches: R0 showed the 256 MiB write stream evicts the input from
// L3 (4x re-reads -> 537 MB HBM); R6 showed unrolled loads re-miss while
// fills are in flight. LDS makes the single-read guarantee structural.
// Traffic: 268 MB write + 88 MB read = 356 MB -> ~53 us at 6.7 TB/s.

typedef float f4 __attribute__((ext_vector_type(4)));

#define T4_PER_B   262144u   // f4 per batch row of x (1048576/4)
#define PREFIX4    384       // 1536 floats / 4 (zero prefix)
#define WIN4       1408      // (8-1)*128 + 512 f4 input window per block

__global__ __launch_bounds__(256) void frame_lds(
    const f4* __restrict__ x4, f4* __restrict__ out4)
{
    __shared__ f4 lds[WIN4];
    const unsigned fg  = blockIdx.x;     // frame group 0..255 (8 frames)
    const unsigned b   = blockIdx.y;     // batch 0..15
    const unsigned tid = threadIdx.x;

    const int      base_i4 = (int)(fg * 1024u) - PREFIX4; // input f4 of lds[0]
    const unsigned in_base = b * T4_PER_B;

    // Phase 1: stage input window (6 strided passes, last partial).
    for (unsigned idx = tid; idx < WIN4; idx += 256u) {
        int i4 = base_i4 + (int)idx;
        f4 v = (f4){0.f, 0.f, 0.f, 0.f};
        if (i4 >= 0) {                    // only fg==0 hits the zero prefix
            v = x4[in_base + (unsigned)i4];
        }
        lds[idx] = v;
    }
    __syncthreads();

    // Phase 2: linear output stream. o = local f4 index 0..4095.
    const unsigned out_base = b * (2048u * 512u) + fg * 4096u;
#pragma unroll
    for (int s = 0; s < 16; ++s) {
        unsigned o  = tid + 256u * (unsigned)s;
        unsigned fl = o >> 9;            // local frame 0..7
        unsigned t4 = o & 511u;          // f4 within frame
        out4[out_base + o] = lds[fl * 128u + t4];
    }
}

extern "C" void kernel_launch(void* const* d_in, const int* in_sizes, int n_in,
                              void* d_out, int out_size, void* d_ws, size_t ws_size,
                              hipStream_t stream) {
    const f4* x4 = (const f4*)d_in[0];
    f4* out4 = (f4*)d_out;
    dim3 block(256);
    dim3 grid(256, 16);   // 2048 frames / 8 per block, 16 batches
    frame_lds<<<grid, block, 0, stream>>>(x4, out4);
}